// Round 3
// baseline (954.992 us; speedup 1.0000x reference)
//
#include <hip/hip_runtime.h>
#include <math.h>

typedef __bf16 bf16;
typedef __bf16 bf16x8 __attribute__((ext_vector_type(8)));
typedef float floatx4 __attribute__((ext_vector_type(4)));

#define S_LEN 2048
#define BATCH 32
#define NHEAD 8
#define KC 19
#define KM 10
#define HKC 152   // 8*19
#define HKM 80    // 8*10
#define NTOT 232  // HKC + HKM
#define NPAD 256

// ================= Phase A: init_misc + kv_proj + zeros + Woq + bq2 =================
// blocks 0..31: P[b], mb, A2 zero
// blocks 32..60: k1/v1 for both tables
// blocks 61..64: zero GT, Bt pad rows, c1, c2
// blocks 65..128: Woq (8 D-rows per block, both branches)
// block 129: bq2 both branches
__global__ __launch_bounds__(256) void prepA(
    const int* __restrict__ em, const int* __restrict__ pmask,
    const int* __restrict__ cmask, const int* __restrict__ mmask,
    const float* __restrict__ ctab, const float* __restrict__ mtab,
    const float* __restrict__ cWk, const float* __restrict__ cbk,
    const float* __restrict__ cWv, const float* __restrict__ cbv,
    const float* __restrict__ mWk, const float* __restrict__ mbk,
    const float* __restrict__ mWv, const float* __restrict__ mbv,
    const float* __restrict__ cWo, const float* __restrict__ cWq,
    const float* __restrict__ mWo, const float* __restrict__ mWq,
    const float* __restrict__ cbo, const float* __restrict__ cbq,
    const float* __restrict__ mbo, const float* __restrict__ mbq,
    float* __restrict__ P, float* __restrict__ A2, float* __restrict__ mb,
    float* __restrict__ k1c, float* __restrict__ v1c,
    float* __restrict__ k1m, float* __restrict__ v1m,
    float* __restrict__ Woqc, float* __restrict__ Woqm,
    float* __restrict__ bq2c, float* __restrict__ bq2m,
    bf16* __restrict__ GT, bf16* __restrict__ Bt,
    float* __restrict__ c1, float* __restrict__ c2)
{
    __shared__ float smem[8192];
    const int blk = blockIdx.x, tid = threadIdx.x;

    if (blk < 32) {
        int* red = (int*)smem;
        int b = blk;
        int s = 0;
        for (int i = tid; i < S_LEN; i += 256) s += em[b*S_LEN+i] * pmask[b*S_LEN+i];
        red[tid] = s; __syncthreads();
        for (int o = 128; o; o >>= 1) { if (tid < o) red[tid] += red[tid+o]; __syncthreads(); }
        if (tid == 0) P[b] = (float)red[0];
        float v = 0.f;
        if (tid < HKC) v = (float)cmask[b*KC + (tid % KC)];
        else if (tid < NTOT) v = (float)mmask[b*KM + ((tid - HKC) % KM)];
        mb[b*NPAD + tid] = v;
        A2[b*NPAD + tid] = 0.f;
    } else if (blk < 61) {
        int r = blk - 32;
        const float* T;  const float* Wk; const float* bk; const float* Wv; const float* bv;
        float* k1; float* v1; int row;
        if (r < KC) { T = ctab; Wk = cWk; bk = cbk; Wv = cWv; bv = cbv; k1 = k1c; v1 = v1c; row = r; }
        else        { T = mtab; Wk = mWk; bk = mbk; Wv = mWv; bv = mbv; k1 = k1m; v1 = v1m; row = r - KC; }
        for (int i = tid; i < 512; i += 256) smem[i] = T[row*512+i];
        __syncthreads();
        for (int j = tid; j < 512; j += 256) {
            float sk = bk[j], sv = bv[j];
            for (int d = 0; d < 512; d++) { float t = smem[d]; sk += t*Wk[d*512+j]; sv += t*Wv[d*512+j]; }
            k1[row*512+j] = sk; v1[row*512+j] = sv;
        }
    } else if (blk < 65) {
        int z = blk - 61;
        for (int i = tid; i < 16384; i += 256) GT[z*16384 + i] = (bf16)0.f;
        for (int i = tid; i < 6144; i += 256) Bt[(size_t)NTOT*1024 + z*6144 + i] = (bf16)0.f;
        if (z == 0) { c1[tid] = 0.f; c2[tid] = 0.f; }
    } else if (blk < 129) {
        int D0 = (blk - 65) * 8;
        for (int i = tid; i < 4096; i += 256) {
            int r = i >> 9, d = i & 511;
            smem[i] = cWo[(size_t)(D0+r)*512 + d];
            smem[4096+i] = mWo[(size_t)(D0+r)*512 + d];
        }
        __syncthreads();
        for (int j = tid; j < 512; j += 256) {
            float ac[8] = {}, am[8] = {};
            for (int t = 0; t < 512; t++) {
                float wc = cWq[t*512+j], wm = mWq[t*512+j];
                #pragma unroll
                for (int r = 0; r < 8; r++) {
                    ac[r] += smem[r*512+t]*wc;
                    am[r] += smem[4096+r*512+t]*wm;
                }
            }
            #pragma unroll
            for (int r = 0; r < 8; r++) {
                Woqc[(size_t)(D0+r)*512 + j] = ac[r];
                Woqm[(size_t)(D0+r)*512 + j] = am[r];
            }
        }
    } else {
        for (int j = tid; j < 512; j += 256) {
            float sc = cbq[j], sm = mbq[j];
            for (int t = 0; t < 512; t++) { sc += cbo[t]*cWq[t*512+j]; sm += mbo[t]*mWq[t*512+j]; }
            bq2c[j] = sc; bq2m[j] = sm;
        }
    }
}

// ================= Phase B: MqTd + MwqD + W2 + c2 =================
// blocks 0..511: D=blk -> MqTd[D][n] (D-major, n global 0..231), MwqDc[D][..], MwqDm[D][..]
// blocks 512..743: W2 row n=blk-512
// block 744: c2
__global__ __launch_bounds__(256) void prepB(
    const float* __restrict__ cWq, const float* __restrict__ mWq,
    const float* __restrict__ Woqc, const float* __restrict__ Woqm,
    const float* __restrict__ k1c, const float* __restrict__ v1c,
    const float* __restrict__ k1m, const float* __restrict__ v1m,
    const float* __restrict__ cWo, const float* __restrict__ mWo,
    const float* __restrict__ bq2c, const float* __restrict__ bq2m,
    float* __restrict__ MqTd, float* __restrict__ MwqDc, float* __restrict__ MwqDm,
    float* __restrict__ W2, float* __restrict__ c2)
{
    __shared__ float smem[16896];
    const int blk = blockIdx.x, tid = threadIdx.x;

    if (blk < 512) {
        int D = blk;
        for (int i = tid; i < 9728; i += 256) smem[i] = k1c[i];
        for (int i = tid; i < 5120; i += 256) smem[9728+i] = k1m[i];
        for (int i = tid; i < 512; i += 256) {
            smem[14848+i] = cWq[(size_t)D*512+i];
            smem[15360+i] = mWq[(size_t)D*512+i];
            smem[15872+i] = Woqc[(size_t)D*512+i];
            smem[16384+i] = Woqm[(size_t)D*512+i];
        }
        __syncthreads();
        if (tid < HKC) {
            int h = tid / KC, k = tid % KC;
            const float* kr = smem + k*512 + h*64;
            float mq = 0.f, mw = 0.f;
            #pragma unroll 16
            for (int d = 0; d < 64; d++) {
                mq += smem[14848 + h*64 + d] * kr[d];
                mw += smem[15872 + h*64 + d] * kr[d];
            }
            MqTd[D*NPAD + tid] = mq;
            MwqDc[D*HKC + tid] = mw;
        }
        if (tid < HKM) {
            int h = tid / KM, k = tid % KM;
            const float* kr = smem + 9728 + k*512 + h*64;
            float mq = 0.f, mw = 0.f;
            #pragma unroll 16
            for (int d = 0; d < 64; d++) {
                mq += smem[15360 + h*64 + d] * kr[d];
                mw += smem[16384 + h*64 + d] * kr[d];
            }
            MqTd[D*NPAD + HKC + tid] = mq;
            MwqDm[D*HKM + tid] = mw;
        }
    } else if (blk < 744) {
        int n = blk - 512;
        const float* v1; const float* Wo; int h, k;
        if (n < HKC) { v1 = v1c; Wo = cWo; h = n / KC; k = n % KC; }
        else         { v1 = v1m; Wo = mWo; h = (n-HKC) / KM; k = (n-HKC) % KM; }
        if (tid < 64) smem[tid] = v1[k*512 + h*64 + tid];
        __syncthreads();
        for (int j = tid; j < 512; j += 256) {
            float s = 0.f;
            #pragma unroll 16
            for (int d = 0; d < 64; d++) s += smem[d] * Wo[(size_t)(h*64+d)*512 + j];
            W2[(size_t)n*512 + j] = s;
        }
    } else {
        if (tid < HKC) {
            int h = tid / KC, k = tid % KC;
            float s = 0.f;
            for (int d = 0; d < 64; d++) s += bq2c[h*64+d] * k1c[k*512 + h*64 + d];
            c2[tid] = 0.125f*s;
        } else if (tid < NTOT) {
            int n = tid - HKC, h = n / KM, k = n % KM;
            float s = 0.f;
            for (int d = 0; d < 64; d++) s += bq2m[h*64+d] * k1m[k*512 + h*64 + d];
            c2[tid] = 0.125f*s;
        }
    }
}

// ================= Phase C: Bt + GT + c1 =================
// blocks 0..127: Bt, 8 Din-rows per block
// blocks 128..359: GT row-block for key n=blk-128
// block 360: c1
__global__ __launch_bounds__(256) void prepC(
    const float* __restrict__ W_lin, const float* __restrict__ b_lin,
    const float* __restrict__ MqTd,
    const float* __restrict__ MwqDc, const float* __restrict__ MwqDm,
    const float* __restrict__ v1c, const float* __restrict__ v1m,
    const float* __restrict__ k1c, const float* __restrict__ k1m,
    const float* __restrict__ cbq, const float* __restrict__ mbq,
    bf16* __restrict__ Bt, bf16* __restrict__ GT, float* __restrict__ c1)
{
    __shared__ float smem[4096];
    const int blk = blockIdx.x, tid = threadIdx.x;

    if (blk < 128) {
        int D0 = blk * 8;
        for (int i = tid; i < 4096; i += 256)
            smem[i] = W_lin[(size_t)(D0 + (i >> 9))*512 + (i & 511)];
        __syncthreads();
        if (tid < NTOT) {
            float acc[8] = {};
            for (int d = 0; d < 512; d++) {
                float m = MqTd[d*NPAD + tid];
                #pragma unroll
                for (int r = 0; r < 8; r++) acc[r] += smem[r*512 + d] * m;
            }
            #pragma unroll
            for (int r = 0; r < 8; r++)
                Bt[(size_t)tid*1024 + D0 + r] = (bf16)(0.125f*acc[r]);
        }
    } else if (blk < 360) {
        int n = blk - 128;
        if (n < HKC) {
            int h = n / KC, k = n % KC;
            if (tid < 64) smem[tid] = v1c[k*512 + h*64 + tid];
            __syncthreads();
            for (int np = tid; np < HKC; np += 256) {
                float s = 0.f;
                #pragma unroll 16
                for (int d = 0; d < 64; d++) s += smem[d] * MwqDc[(h*64+d)*HKC + np];
                GT[(size_t)np*NPAD + n] = (bf16)(0.125f*s);
            }
        } else {
            int nm = n - HKC, h = nm / KM, k = nm % KM;
            if (tid < 64) smem[tid] = v1m[k*512 + h*64 + tid];
            __syncthreads();
            for (int np = tid; np < HKM; np += 256) {
                float s = 0.f;
                #pragma unroll 16
                for (int d = 0; d < 64; d++) s += smem[d] * MwqDm[(h*64+d)*HKM + np];
                GT[(size_t)(HKC+np)*NPAD + n] = (bf16)(0.125f*s);
            }
        }
    } else {
        if (tid < NTOT) {
            float s = 0.f;
            for (int D = 0; D < 512; D++) s += b_lin[D] * MqTd[D*NPAD + tid];
            if (tid < HKC) {
                int h = tid / KC, k = tid % KC;
                for (int d = 0; d < 64; d++) s += cbq[h*64+d] * k1c[k*512 + h*64 + d];
            } else {
                int n = tid - HKC, h = n / KM, k = n % KM;
                for (int d = 0; d < 64; d++) s += mbq[h*64+d] * k1m[k*512 + h*64 + d];
            }
            c1[tid] = 0.125f*s;
        }
    }
}

// ================= G1: logits1 = emb @ Bt^T + bias ; softmax per head -> av1 (bf16) =================
__global__ __launch_bounds__(256, 2) void g1_kernel(const float* __restrict__ emb,
                                                    const bf16* __restrict__ Bt,
                                                    const float* __restrict__ c1,
                                                    const float* __restrict__ mb,
                                                    bf16* __restrict__ av1)
{
    __shared__ union UU {
        struct { bf16 As[128*40]; bf16 Bs[256*40]; } s;
        bf16 Ls[128*264];
    } u;
    __shared__ float bias[256];
    const int tid = threadIdx.x;
    const int m0 = blockIdx.x*128, b = blockIdx.x >> 4;
    bias[tid] = c1[tid] + mb[b*NPAD + tid];
    const int wave = tid >> 6, lane = tid & 63, lr = lane & 15, kg = lane >> 4;
    floatx4 acc[8][4] = {};
    const int arow = tid >> 1, acol = (tid & 1)*16;
    const float* ap = emb + (size_t)(m0 + arow)*1024 + acol;
    bf16* asw = u.s.As + arow*40 + acol;
    const bf16* bp = Bt + (size_t)tid*1024;
    bf16* bsw = u.s.Bs + tid*40;
    const bf16* afp = u.s.As + lr*40 + kg*8;
    const bf16* bfp = u.s.Bs + (wave*64 + lr)*40 + kg*8;

    for (int k0 = 0; k0 < 1024; k0 += 32) {
        float4 f0 = *(const float4*)(ap + k0);
        float4 f1 = *(const float4*)(ap + k0 + 4);
        float4 f2 = *(const float4*)(ap + k0 + 8);
        float4 f3 = *(const float4*)(ap + k0 + 12);
        uint4 b0 = *(const uint4*)(bp + k0);
        uint4 b1 = *(const uint4*)(bp + k0 + 8);
        uint4 b2 = *(const uint4*)(bp + k0 + 16);
        uint4 b3 = *(const uint4*)(bp + k0 + 24);
        __syncthreads();
        bf16x8 p0, p1;
        p0[0]=(bf16)f0.x; p0[1]=(bf16)f0.y; p0[2]=(bf16)f0.z; p0[3]=(bf16)f0.w;
        p0[4]=(bf16)f1.x; p0[5]=(bf16)f1.y; p0[6]=(bf16)f1.z; p0[7]=(bf16)f1.w;
        p1[0]=(bf16)f2.x; p1[1]=(bf16)f2.y; p1[2]=(bf16)f2.z; p1[3]=(bf16)f2.w;
        p1[4]=(bf16)f3.x; p1[5]=(bf16)f3.y; p1[6]=(bf16)f3.z; p1[7]=(bf16)f3.w;
        *(bf16x8*)asw = p0; *(bf16x8*)(asw + 8) = p1;
        *(uint4*)bsw = b0; *(uint4*)(bsw + 8) = b1; *(uint4*)(bsw + 16) = b2; *(uint4*)(bsw + 24) = b3;
        __syncthreads();
        bf16x8 af[8], bfr[4];
        #pragma unroll
        for (int mi = 0; mi < 8; mi++) af[mi] = *(const bf16x8*)(afp + mi*16*40);
        #pragma unroll
        for (int nt = 0; nt < 4; nt++) bfr[nt] = *(const bf16x8*)(bfp + nt*16*40);
        #pragma unroll
        for (int mi = 0; mi < 8; mi++)
            #pragma unroll
            for (int nt = 0; nt < 4; nt++)
                acc[mi][nt] = __builtin_amdgcn_mfma_f32_16x16x32_bf16(af[mi], bfr[nt], acc[mi][nt], 0, 0, 0);
    }
    __syncthreads();
    #pragma unroll
    for (int nt = 0; nt < 4; nt++) {
        int col = wave*64 + nt*16 + lr;
        float bb = bias[col];
        #pragma unroll
        for (int mi = 0; mi < 8; mi++) {
            int row = mi*16 + kg*4;
            #pragma unroll
            for (int r = 0; r < 4; r++)
                u.Ls[(row + r)*264 + col] = (bf16)(acc[mi][nt][r] + bb);
        }
    }
    __syncthreads();
    {
        int row = tid & 127;
        bf16* Lr = u.Ls + row*264;
        if (tid < 128) {
            for (int h = 0; h < NHEAD; h++) {
                float lv[KC]; float m = -1e30f;
                #pragma unroll
                for (int j = 0; j < KC; j++) { lv[j] = (float)Lr[h*KC + j]; m = fmaxf(m, lv[j]); }
                float s = 0.f;
                #pragma unroll
                for (int j = 0; j < KC; j++) { lv[j] = __expf(lv[j] - m); s += lv[j]; }
                float inv = 1.f / s;
                #pragma unroll
                for (int j = 0; j < KC; j++) Lr[h*KC + j] = (bf16)(lv[j]*inv);
            }
        } else {
            for (int h = 0; h < NHEAD; h++) {
                float lv[KM]; float m = -1e30f;
                #pragma unroll
                for (int j = 0; j < KM; j++) { lv[j] = (float)Lr[HKC + h*KM + j]; m = fmaxf(m, lv[j]); }
                float s = 0.f;
                #pragma unroll
                for (int j = 0; j < KM; j++) { lv[j] = __expf(lv[j] - m); s += lv[j]; }
                float inv = 1.f / s;
                #pragma unroll
                for (int j = 0; j < KM; j++) Lr[HKC + h*KM + j] = (bf16)(lv[j]*inv);
            }
            for (int c = NTOT; c < NPAD; c++) Lr[c] = (bf16)0.f;
        }
    }
    __syncthreads();
    for (int c = tid; c < 4096; c += 256) {
        int row = c >> 5, c8 = (c & 31)*8;
        *(uint4*)(av1 + (size_t)(m0 + row)*NPAD + c8) = *(const uint4*)(u.Ls + row*264 + c8);
    }
}

// ================= G2: logits2 = av1 @ GT^T + bias ; softmax ; pool -> A2 atomics =================
__global__ __launch_bounds__(256, 2) void g2_kernel(const bf16* __restrict__ av1,
                                                    const bf16* __restrict__ GT,
                                                    const float* __restrict__ c2,
                                                    const float* __restrict__ mb,
                                                    float* __restrict__ A2)
{
    __shared__ union UU {
        struct { bf16 As[128*40]; bf16 Bs[256*40]; } s;
        bf16 Ls[128*264];
    } u;
    __shared__ float bias[256];
    const int tid = threadIdx.x;
    const int m0 = blockIdx.x*128, b = blockIdx.x >> 4;
    bias[tid] = c2[tid] + mb[b*NPAD + tid];
    const int wave = tid >> 6, lane = tid & 63, lr = lane & 15, kg = lane >> 4;
    floatx4 acc[8][4] = {};
    const int arow = tid >> 1, acol = (tid & 1)*16;
    const bf16* ap = av1 + (size_t)(m0 + arow)*NPAD + acol;
    bf16* asw = u.s.As + arow*40 + acol;
    const bf16* bp = GT + (size_t)tid*NPAD;
    bf16* bsw = u.s.Bs + tid*40;
    const bf16* afp = u.s.As + lr*40 + kg*8;
    const bf16* bfp = u.s.Bs + (wave*64 + lr)*40 + kg*8;

    for (int k0 = 0; k0 < 256; k0 += 32) {
        uint4 a0 = *(const uint4*)(ap + k0);
        uint4 a1 = *(const uint4*)(ap + k0 + 8);
        uint4 b0 = *(const uint4*)(bp + k0);
        uint4 b1 = *(const uint4*)(bp + k0 + 8);
        uint4 b2 = *(const uint4*)(bp + k0 + 16);
        uint4 b3 = *(const uint4*)(bp + k0 + 24);
        __syncthreads();
        *(uint4*)asw = a0; *(uint4*)(asw + 8) = a1;
        *(uint4*)bsw = b0; *(uint4*)(bsw + 8) = b1; *(uint4*)(bsw + 16) = b2; *(uint4*)(bsw + 24) = b3;
        __syncthreads();
        bf16x8 af[8], bfr[4];
        #pragma unroll
        for (int mi = 0; mi < 8; mi++) af[mi] = *(const bf16x8*)(afp + mi*16*40);
        #pragma unroll
        for (int nt = 0; nt < 4; nt++) bfr[nt] = *(const bf16x8*)(bfp + nt*16*40);
        #pragma unroll
        for (int mi = 0; mi < 8; mi++)
            #pragma unroll
            for (int nt = 0; nt < 4; nt++)
                acc[mi][nt] = __builtin_amdgcn_mfma_f32_16x16x32_bf16(af[mi], bfr[nt], acc[mi][nt], 0, 0, 0);
    }
    __syncthreads();
    #pragma unroll
    for (int nt = 0; nt < 4; nt++) {
        int col = wave*64 + nt*16 + lr;
        float bb = bias[col];
        #pragma unroll
        for (int mi = 0; mi < 8; mi++) {
            int row = mi*16 + kg*4;
            #pragma unroll
            for (int r = 0; r < 4; r++)
                u.Ls[(row + r)*264 + col] = (bf16)(acc[mi][nt][r] + bb);
        }
    }
    __syncthreads();
    {
        int row = tid & 127;
        bf16* Lr = u.Ls + row*264;
        if (tid < 128) {
            for (int h = 0; h < NHEAD; h++) {
                float lv[KC]; float m = -1e30f;
                #pragma unroll
                for (int j = 0; j < KC; j++) { lv[j] = (float)Lr[h*KC + j]; m = fmaxf(m, lv[j]); }
                float s = 0.f;
                #pragma unroll
                for (int j = 0; j < KC; j++) { lv[j] = __expf(lv[j] - m); s += lv[j]; }
                float inv = 1.f / s;
                #pragma unroll
                for (int j = 0; j < KC; j++) Lr[h*KC + j] = (bf16)(lv[j]*inv);
            }
        } else {
            for (int h = 0; h < NHEAD; h++) {
                float lv[KM]; float m = -1e30f;
                #pragma unroll
                for (int j = 0; j < KM; j++) { lv[j] = (float)Lr[HKC + h*KM + j]; m = fmaxf(m, lv[j]); }
                float s = 0.f;
                #pragma unroll
                for (int j = 0; j < KM; j++) { lv[j] = __expf(lv[j] - m); s += lv[j]; }
                float inv = 1.f / s;
                #pragma unroll
                for (int j = 0; j < KM; j++) Lr[HKC + h*KM + j] = (bf16)(lv[j]*inv);
            }
        }
    }
    __syncthreads();
    {
        float s = 0.f;
        for (int r = 0; r < 128; r++) s += (float)u.Ls[r*264 + tid];
        if (tid < NTOT) atomicAdd(&A2[b*NPAD + tid], s);
    }
}

// ---------------- finalize ----------------
__global__ __launch_bounds__(256) void finalize_kernel(const float* __restrict__ A2, const float* __restrict__ W2,
                                                       const float* __restrict__ cbo, const float* __restrict__ mbo,
                                                       const float* __restrict__ P, float* __restrict__ out)
{
    __shared__ float a[NTOT];
    int b = blockIdx.x, tid = threadIdx.x;
    if (tid < NTOT) a[tid] = A2[b*NPAD + tid];
    __syncthreads();
    float invP = 1.f / P[b];
    for (int j = tid; j < 512; j += 256) {
        float pc = 2048.f*cbo[j], pm = 2048.f*mbo[j];
        for (int n = 0; n < HKC; n++) pc += a[n]*W2[n*512 + j];
        for (int n = HKC; n < NTOT; n++) pm += a[n]*W2[n*512 + j];
        out[b*512 + j] = pc*invP;
        out[BATCH*512 + b*512 + j] = (pc - pm)*invP;
    }
}

extern "C" void kernel_launch(void* const* d_in, const int* in_sizes, int n_in,
                              void* d_out, int out_size, void* d_ws, size_t ws_size,
                              hipStream_t stream)
{
    (void)in_sizes; (void)n_in; (void)out_size;
    const float* emb   = (const float*)d_in[0];
    const int* emask   = (const int*)d_in[1];
    const int* pmask   = (const int*)d_in[2];
    /* d_in[3] frame_mask: cancels in softmax */
    const int* cmask   = (const int*)d_in[4];
    const int* mmask   = (const int*)d_in[5];
    const float* W_lin = (const float*)d_in[6];
    const float* b_lin = (const float*)d_in[7];
    const float* ctab  = (const float*)d_in[8];
    const float* mtab  = (const float*)d_in[9];
    const float* cWq = (const float*)d_in[10]; const float* cbq = (const float*)d_in[11];
    const float* cWk = (const float*)d_in[12]; const float* cbk = (const float*)d_in[13];
    const float* cWv = (const float*)d_in[14]; const float* cbv = (const float*)d_in[15];
    const float* cWo = (const float*)d_in[16]; const float* cbo = (const float*)d_in[17];
    const float* mWq = (const float*)d_in[18]; const float* mbq = (const float*)d_in[19];
    const float* mWk = (const float*)d_in[20]; const float* mbk = (const float*)d_in[21];
    const float* mWv = (const float*)d_in[22]; const float* mbv = (const float*)d_in[23];
    const float* mWo = (const float*)d_in[24]; const float* mbo = (const float*)d_in[25];
    float* outp = (float*)d_out;

    if (ws_size < 40000000UL) return;

    char* ws = (char*)d_ws;
    size_t o = 0;
    bf16* av1   = (bf16*)(ws + o); o += (size_t)65536*NPAD*2;   // 33.5 MB
    bf16* Bt    = (bf16*)(ws + o); o += 256*1024*2;
    bf16* GT    = (bf16*)(ws + o); o += NPAD*NPAD*2;
    float* k1c  = (float*)(ws + o); o += KC*512*4;
    float* v1c  = (float*)(ws + o); o += KC*512*4;
    float* k1m  = (float*)(ws + o); o += KM*512*4;
    float* v1m  = (float*)(ws + o); o += KM*512*4;
    float* MqTd = (float*)(ws + o); o += (size_t)512*NPAD*4;
    float* MwqDc= (float*)(ws + o); o += (size_t)512*HKC*4;
    float* MwqDm= (float*)(ws + o); o += (size_t)512*HKM*4;
    float* Woqc = (float*)(ws + o); o += (size_t)512*512*4;
    float* Woqm = (float*)(ws + o); o += (size_t)512*512*4;
    float* W2   = (float*)(ws + o); o += (size_t)NTOT*512*4;
    float* c1   = (float*)(ws + o); o += NPAD*4;
    float* c2   = (float*)(ws + o); o += NPAD*4;
    float* bq2c = (float*)(ws + o); o += 512*4;
    float* bq2m = (float*)(ws + o); o += 512*4;
    float* mbt  = (float*)(ws + o); o += BATCH*NPAD*4;
    float* P    = (float*)(ws + o); o += 128;
    float* A2   = (float*)(ws + o); o += BATCH*NPAD*4;

    dim3 blk(256);

    prepA<<<dim3(130), blk, 0, stream>>>(emask, pmask, cmask, mmask, ctab, mtab,
                                         cWk, cbk, cWv, cbv, mWk, mbk, mWv, mbv,
                                         cWo, cWq, mWo, mWq, cbo, cbq, mbo, mbq,
                                         P, A2, mbt, k1c, v1c, k1m, v1m,
                                         Woqc, Woqm, bq2c, bq2m, GT, Bt, c1, c2);
    prepB<<<dim3(745), blk, 0, stream>>>(cWq, mWq, Woqc, Woqm, k1c, v1c, k1m, v1m,
                                         cWo, mWo, bq2c, bq2m,
                                         MqTd, MwqDc, MwqDm, W2, c2);
    prepC<<<dim3(361), blk, 0, stream>>>(W_lin, b_lin, MqTd, MwqDc, MwqDm,
                                         v1c, v1m, k1c, k1m, cbq, mbq,
                                         Bt, GT, c1);
    g1_kernel<<<dim3(512), blk, 0, stream>>>(emb, Bt, c1, mbt, av1);
    g2_kernel<<<dim3(512), blk, 0, stream>>>(av1, GT, c2, mbt, A2);
    finalize_kernel<<<dim3(BATCH), blk, 0, stream>>>(A2, W2, cbo, mbo, P, outp);
}

// Round 4
// 642.613 us; speedup vs baseline: 1.4861x; 1.4861x over previous
//
#include <hip/hip_runtime.h>
#include <math.h>

typedef __bf16 bf16;
typedef __bf16 bf16x8 __attribute__((ext_vector_type(8)));
typedef float floatx4 __attribute__((ext_vector_type(4)));

#define S_LEN 2048
#define BATCH 32
#define NHEAD 8
#define KC 19
#define KM 10
#define HKC 152   // 8*19
#define HKM 80    // 8*10
#define NTOT 232  // HKC + HKM
#define NPAD 256

// ================= prep1: init + kv_proj + zeros =================
// blocks 0..31: P[b], mb, A2 zero
// blocks 32..60: k1/v1 rows for both tables
// blocks 61..64: zero GT, Bt pad rows, c1, c2
__global__ __launch_bounds__(256) void prep1(
    const int* __restrict__ em, const int* __restrict__ pmask,
    const int* __restrict__ cmask, const int* __restrict__ mmask,
    const float* __restrict__ ctab, const float* __restrict__ mtab,
    const float* __restrict__ cWk, const float* __restrict__ cbk,
    const float* __restrict__ cWv, const float* __restrict__ cbv,
    const float* __restrict__ mWk, const float* __restrict__ mbk,
    const float* __restrict__ mWv, const float* __restrict__ mbv,
    float* __restrict__ P, float* __restrict__ A2, float* __restrict__ mb,
    float* __restrict__ k1c, float* __restrict__ v1c,
    float* __restrict__ k1m, float* __restrict__ v1m,
    bf16* __restrict__ GT, bf16* __restrict__ Bt,
    float* __restrict__ c1, float* __restrict__ c2)
{
    __shared__ float smem[512];
    const int blk = blockIdx.x, tid = threadIdx.x;

    if (blk < 32) {
        int* red = (int*)smem;
        int b = blk;
        int s = 0;
        for (int i = tid; i < S_LEN; i += 256) s += em[b*S_LEN+i] * pmask[b*S_LEN+i];
        red[tid] = s; __syncthreads();
        for (int o = 128; o; o >>= 1) { if (tid < o) red[tid] += red[tid+o]; __syncthreads(); }
        if (tid == 0) P[b] = (float)red[0];
        float v = 0.f;
        if (tid < HKC) v = (float)cmask[b*KC + (tid % KC)];
        else if (tid < NTOT) v = (float)mmask[b*KM + ((tid - HKC) % KM)];
        mb[b*NPAD + tid] = v;
        A2[b*NPAD + tid] = 0.f;
    } else if (blk < 61) {
        int r = blk - 32;
        const float* T;  const float* Wk; const float* bk; const float* Wv; const float* bv;
        float* k1; float* v1; int row;
        if (r < KC) { T = ctab; Wk = cWk; bk = cbk; Wv = cWv; bv = cbv; k1 = k1c; v1 = v1c; row = r; }
        else        { T = mtab; Wk = mWk; bk = mbk; Wv = mWv; bv = mbv; k1 = k1m; v1 = v1m; row = r - KC; }
        for (int i = tid; i < 512; i += 256) smem[i] = T[row*512+i];
        __syncthreads();
        for (int j = tid; j < 512; j += 256) {
            float sk = bk[j], sv = bv[j];
            for (int d = 0; d < 512; d++) { float t = smem[d]; sk += t*Wk[d*512+j]; sv += t*Wv[d*512+j]; }
            k1[row*512+j] = sk; v1[row*512+j] = sv;
        }
    } else {
        int z = blk - 61;
        for (int i = tid; i < 16384; i += 256) GT[z*16384 + i] = (bf16)0.f;
        for (int i = tid; i < 6144; i += 256) Bt[(size_t)NTOT*1024 + z*6144 + i] = (bf16)0.f;
        if (z == 0) { c1[tid] = 0.f; c2[tid] = 0.f; }
    }
}

// ================= prep2: MqTd + W2 =================
// blocks 0..511: D=blk -> MqTd[D][n] (n global 0..231, D-major)
// blocks 512..743: W2 row n=blk-512
__global__ __launch_bounds__(256) void prep2(
    const float* __restrict__ cWq, const float* __restrict__ mWq,
    const float* __restrict__ k1c, const float* __restrict__ v1c,
    const float* __restrict__ k1m, const float* __restrict__ v1m,
    const float* __restrict__ cWo, const float* __restrict__ mWo,
    float* __restrict__ MqTd, float* __restrict__ W2)
{
    __shared__ float smem[15872];
    const int blk = blockIdx.x, tid = threadIdx.x;

    if (blk < 512) {
        int D = blk;
        for (int i = tid; i < 9728; i += 256) smem[i] = k1c[i];
        for (int i = tid; i < 5120; i += 256) smem[9728+i] = k1m[i];
        for (int i = tid; i < 512; i += 256) {
            smem[14848+i] = cWq[(size_t)D*512+i];
            smem[15360+i] = mWq[(size_t)D*512+i];
        }
        __syncthreads();
        if (tid < HKC) {
            int h = tid / KC, k = tid % KC;
            const float* kr = smem + k*512 + h*64;
            float mq = 0.f;
            #pragma unroll 16
            for (int d = 0; d < 64; d++) mq += smem[14848 + h*64 + d] * kr[d];
            MqTd[D*NPAD + tid] = mq;
        }
        if (tid < HKM) {
            int h = tid / KM, k = tid % KM;
            const float* kr = smem + 9728 + k*512 + h*64;
            float mq = 0.f;
            #pragma unroll 16
            for (int d = 0; d < 64; d++) mq += smem[15360 + h*64 + d] * kr[d];
            MqTd[D*NPAD + HKC + tid] = mq;
        }
    } else {
        int n = blk - 512;
        const float* v1; const float* Wo; int h, k;
        if (n < HKC) { v1 = v1c; Wo = cWo; h = n / KC; k = n % KC; }
        else         { v1 = v1m; Wo = mWo; h = (n-HKC) / KM; k = (n-HKC) % KM; }
        if (tid < 64) smem[tid] = v1[k*512 + h*64 + tid];
        __syncthreads();
        for (int j = tid; j < 512; j += 256) {
            float s = 0.f;
            #pragma unroll 16
            for (int d = 0; d < 64; d++) s += smem[d] * Wo[(size_t)(h*64+d)*512 + j];
            W2[(size_t)n*512 + j] = s;
        }
    }
}

// ================= prep3: GT + Bt + c1/c2 =================
// blocks 0..231:   GT col n=blk:  GT[np][n] = 0.125 * sum_t W2[n,t]*MqTd[t][np]
// blocks 232..359: Bt, 8 Din-rows per block
// block 360:       c1 and c2
__global__ __launch_bounds__(256) void prep3(
    const float* __restrict__ W_lin, const float* __restrict__ b_lin,
    const float* __restrict__ MqTd, const float* __restrict__ W2,
    const float* __restrict__ k1c, const float* __restrict__ k1m,
    const float* __restrict__ cbq, const float* __restrict__ mbq,
    const float* __restrict__ cbo, const float* __restrict__ mbo,
    bf16* __restrict__ Bt, bf16* __restrict__ GT, float* __restrict__ c1, float* __restrict__ c2)
{
    __shared__ float smem[4096];
    const int blk = blockIdx.x, tid = threadIdx.x;

    if (blk < NTOT) {
        int n = blk;
        for (int i = tid; i < 512; i += 256) smem[i] = W2[(size_t)n*512 + i];
        __syncthreads();
        if (n < HKC) {
            for (int np = tid; np < HKC; np += 256) {
                float s = 0.f;
                for (int t = 0; t < 512; t++) s += smem[t] * MqTd[t*NPAD + np];
                GT[(size_t)np*NPAD + n] = (bf16)(0.125f*s);
            }
        } else {
            for (int np = tid; np < HKM; np += 256) {
                float s = 0.f;
                for (int t = 0; t < 512; t++) s += smem[t] * MqTd[t*NPAD + HKC + np];
                GT[(size_t)(HKC+np)*NPAD + n] = (bf16)(0.125f*s);
            }
        }
    } else if (blk < 360) {
        int D0 = (blk - NTOT) * 8;
        for (int i = tid; i < 4096; i += 256)
            smem[i] = W_lin[(size_t)(D0 + (i >> 9))*512 + (i & 511)];
        __syncthreads();
        if (tid < NTOT) {
            float acc[8] = {};
            for (int d = 0; d < 512; d++) {
                float m = MqTd[d*NPAD + tid];
                #pragma unroll
                for (int r = 0; r < 8; r++) acc[r] += smem[r*512 + d] * m;
            }
            #pragma unroll
            for (int r = 0; r < 8; r++)
                Bt[(size_t)tid*1024 + D0 + r] = (bf16)(0.125f*acc[r]);
        }
    } else {
        // c1[n] = 0.125*(sum_D b_lin[D]*MqTd[D][n] + sum_d bq*k1)
        // c2[n] = 0.125*(sum_D bo[D]  *MqTd[D][n] + sum_d bq*k1)
        for (int i = tid; i < 512; i += 256) {
            smem[i] = b_lin[i];
            smem[512+i] = cbo[i];
            smem[1024+i] = mbo[i];
        }
        __syncthreads();
        if (tid < NTOT) {
            bool cult = tid < HKC;
            const float* bo_s = cult ? (smem+512) : (smem+1024);
            float sA = 0.f, sB = 0.f;
            for (int D = 0; D < 512; D++) {
                float m = MqTd[D*NPAD + tid];
                sA += smem[D]*m;
                sB += bo_s[D]*m;
            }
            float skq = 0.f;
            if (cult) {
                int h = tid / KC, k = tid % KC;
                for (int d = 0; d < 64; d++) skq += cbq[h*64+d] * k1c[k*512 + h*64 + d];
            } else {
                int nm = tid - HKC, h = nm / KM, k = nm % KM;
                for (int d = 0; d < 64; d++) skq += mbq[h*64+d] * k1m[k*512 + h*64 + d];
            }
            c1[tid] = 0.125f*(sA + skq);
            c2[tid] = 0.125f*(sB + skq);
        }
    }
}

// ================= G1: logits1 = emb @ Bt^T + bias ; softmax per head -> av1 (bf16) =================
__global__ __launch_bounds__(256, 2) void g1_kernel(const float* __restrict__ emb,
                                                    const bf16* __restrict__ Bt,
                                                    const float* __restrict__ c1,
                                                    const float* __restrict__ mb,
                                                    bf16* __restrict__ av1)
{
    __shared__ union UU {
        struct { bf16 As[128*40]; bf16 Bs[256*40]; } s;
        bf16 Ls[128*264];
    } u;
    __shared__ float bias[256];
    const int tid = threadIdx.x;
    const int m0 = blockIdx.x*128, b = blockIdx.x >> 4;
    bias[tid] = c1[tid] + mb[b*NPAD + tid];
    const int wave = tid >> 6, lane = tid & 63, lr = lane & 15, kg = lane >> 4;
    floatx4 acc[8][4] = {};
    const int arow = tid >> 1, acol = (tid & 1)*16;
    const float* ap = emb + (size_t)(m0 + arow)*1024 + acol;
    bf16* asw = u.s.As + arow*40 + acol;
    const bf16* bp = Bt + (size_t)tid*1024;
    bf16* bsw = u.s.Bs + tid*40;
    const bf16* afp = u.s.As + lr*40 + kg*8;
    const bf16* bfp = u.s.Bs + (wave*64 + lr)*40 + kg*8;

    for (int k0 = 0; k0 < 1024; k0 += 32) {
        float4 f0 = *(const float4*)(ap + k0);
        float4 f1 = *(const float4*)(ap + k0 + 4);
        float4 f2 = *(const float4*)(ap + k0 + 8);
        float4 f3 = *(const float4*)(ap + k0 + 12);
        uint4 b0 = *(const uint4*)(bp + k0);
        uint4 b1 = *(const uint4*)(bp + k0 + 8);
        uint4 b2 = *(const uint4*)(bp + k0 + 16);
        uint4 b3 = *(const uint4*)(bp + k0 + 24);
        __syncthreads();
        bf16x8 p0, p1;
        p0[0]=(bf16)f0.x; p0[1]=(bf16)f0.y; p0[2]=(bf16)f0.z; p0[3]=(bf16)f0.w;
        p0[4]=(bf16)f1.x; p0[5]=(bf16)f1.y; p0[6]=(bf16)f1.z; p0[7]=(bf16)f1.w;
        p1[0]=(bf16)f2.x; p1[1]=(bf16)f2.y; p1[2]=(bf16)f2.z; p1[3]=(bf16)f2.w;
        p1[4]=(bf16)f3.x; p1[5]=(bf16)f3.y; p1[6]=(bf16)f3.z; p1[7]=(bf16)f3.w;
        *(bf16x8*)asw = p0; *(bf16x8*)(asw + 8) = p1;
        *(uint4*)bsw = b0; *(uint4*)(bsw + 8) = b1; *(uint4*)(bsw + 16) = b2; *(uint4*)(bsw + 24) = b3;
        __syncthreads();
        bf16x8 af[8], bfr[4];
        #pragma unroll
        for (int mi = 0; mi < 8; mi++) af[mi] = *(const bf16x8*)(afp + mi*16*40);
        #pragma unroll
        for (int nt = 0; nt < 4; nt++) bfr[nt] = *(const bf16x8*)(bfp + nt*16*40);
        #pragma unroll
        for (int mi = 0; mi < 8; mi++)
            #pragma unroll
            for (int nt = 0; nt < 4; nt++)
                acc[mi][nt] = __builtin_amdgcn_mfma_f32_16x16x32_bf16(af[mi], bfr[nt], acc[mi][nt], 0, 0, 0);
    }
    __syncthreads();
    #pragma unroll
    for (int nt = 0; nt < 4; nt++) {
        int col = wave*64 + nt*16 + lr;
        float bb = bias[col];
        #pragma unroll
        for (int mi = 0; mi < 8; mi++) {
            int row = mi*16 + kg*4;
            #pragma unroll
            for (int r = 0; r < 4; r++)
                u.Ls[(row + r)*264 + col] = (bf16)(acc[mi][nt][r] + bb);
        }
    }
    __syncthreads();
    {
        int row = tid & 127;
        bf16* Lr = u.Ls + row*264;
        if (tid < 128) {
            for (int h = 0; h < NHEAD; h++) {
                float lv[KC]; float m = -1e30f;
                #pragma unroll
                for (int j = 0; j < KC; j++) { lv[j] = (float)Lr[h*KC + j]; m = fmaxf(m, lv[j]); }
                float s = 0.f;
                #pragma unroll
                for (int j = 0; j < KC; j++) { lv[j] = __expf(lv[j] - m); s += lv[j]; }
                float inv = 1.f / s;
                #pragma unroll
                for (int j = 0; j < KC; j++) Lr[h*KC + j] = (bf16)(lv[j]*inv);
            }
        } else {
            for (int h = 0; h < NHEAD; h++) {
                float lv[KM]; float m = -1e30f;
                #pragma unroll
                for (int j = 0; j < KM; j++) { lv[j] = (float)Lr[HKC + h*KM + j]; m = fmaxf(m, lv[j]); }
                float s = 0.f;
                #pragma unroll
                for (int j = 0; j < KM; j++) { lv[j] = __expf(lv[j] - m); s += lv[j]; }
                float inv = 1.f / s;
                #pragma unroll
                for (int j = 0; j < KM; j++) Lr[HKC + h*KM + j] = (bf16)(lv[j]*inv);
            }
            for (int c = NTOT; c < NPAD; c++) Lr[c] = (bf16)0.f;
        }
    }
    __syncthreads();
    for (int c = tid; c < 4096; c += 256) {
        int row = c >> 5, c8 = (c & 31)*8;
        *(uint4*)(av1 + (size_t)(m0 + row)*NPAD + c8) = *(const uint4*)(u.Ls + row*264 + c8);
    }
}

// ================= G2: logits2 = av1 @ GT^T + bias ; softmax ; pool -> A2 atomics =================
__global__ __launch_bounds__(256, 2) void g2_kernel(const bf16* __restrict__ av1,
                                                    const bf16* __restrict__ GT,
                                                    const float* __restrict__ c2,
                                                    const float* __restrict__ mb,
                                                    float* __restrict__ A2)
{
    __shared__ union UU {
        struct { bf16 As[128*40]; bf16 Bs[256*40]; } s;
        bf16 Ls[128*264];
    } u;
    __shared__ float bias[256];
    const int tid = threadIdx.x;
    const int m0 = blockIdx.x*128, b = blockIdx.x >> 4;
    bias[tid] = c2[tid] + mb[b*NPAD + tid];
    const int wave = tid >> 6, lane = tid & 63, lr = lane & 15, kg = lane >> 4;
    floatx4 acc[8][4] = {};
    const int arow = tid >> 1, acol = (tid & 1)*16;
    const bf16* ap = av1 + (size_t)(m0 + arow)*NPAD + acol;
    bf16* asw = u.s.As + arow*40 + acol;
    const bf16* bp = GT + (size_t)tid*NPAD;
    bf16* bsw = u.s.Bs + tid*40;
    const bf16* afp = u.s.As + lr*40 + kg*8;
    const bf16* bfp = u.s.Bs + (wave*64 + lr)*40 + kg*8;

    for (int k0 = 0; k0 < 256; k0 += 32) {
        uint4 a0 = *(const uint4*)(ap + k0);
        uint4 a1 = *(const uint4*)(ap + k0 + 8);
        uint4 b0 = *(const uint4*)(bp + k0);
        uint4 b1 = *(const uint4*)(bp + k0 + 8);
        uint4 b2 = *(const uint4*)(bp + k0 + 16);
        uint4 b3 = *(const uint4*)(bp + k0 + 24);
        __syncthreads();
        *(uint4*)asw = a0; *(uint4*)(asw + 8) = a1;
        *(uint4*)bsw = b0; *(uint4*)(bsw + 8) = b1; *(uint4*)(bsw + 16) = b2; *(uint4*)(bsw + 24) = b3;
        __syncthreads();
        bf16x8 af[8], bfr[4];
        #pragma unroll
        for (int mi = 0; mi < 8; mi++) af[mi] = *(const bf16x8*)(afp + mi*16*40);
        #pragma unroll
        for (int nt = 0; nt < 4; nt++) bfr[nt] = *(const bf16x8*)(bfp + nt*16*40);
        #pragma unroll
        for (int mi = 0; mi < 8; mi++)
            #pragma unroll
            for (int nt = 0; nt < 4; nt++)
                acc[mi][nt] = __builtin_amdgcn_mfma_f32_16x16x32_bf16(af[mi], bfr[nt], acc[mi][nt], 0, 0, 0);
    }
    __syncthreads();
    #pragma unroll
    for (int nt = 0; nt < 4; nt++) {
        int col = wave*64 + nt*16 + lr;
        float bb = bias[col];
        #pragma unroll
        for (int mi = 0; mi < 8; mi++) {
            int row = mi*16 + kg*4;
            #pragma unroll
            for (int r = 0; r < 4; r++)
                u.Ls[(row + r)*264 + col] = (bf16)(acc[mi][nt][r] + bb);
        }
    }
    __syncthreads();
    {
        int row = tid & 127;
        bf16* Lr = u.Ls + row*264;
        if (tid < 128) {
            for (int h = 0; h < NHEAD; h++) {
                float lv[KC]; float m = -1e30f;
                #pragma unroll
                for (int j = 0; j < KC; j++) { lv[j] = (float)Lr[h*KC + j]; m = fmaxf(m, lv[j]); }
                float s = 0.f;
                #pragma unroll
                for (int j = 0; j < KC; j++) { lv[j] = __expf(lv[j] - m); s += lv[j]; }
                float inv = 1.f / s;
                #pragma unroll
                for (int j = 0; j < KC; j++) Lr[h*KC + j] = (bf16)(lv[j]*inv);
            }
        } else {
            for (int h = 0; h < NHEAD; h++) {
                float lv[KM]; float m = -1e30f;
                #pragma unroll
                for (int j = 0; j < KM; j++) { lv[j] = (float)Lr[HKC + h*KM + j]; m = fmaxf(m, lv[j]); }
                float s = 0.f;
                #pragma unroll
                for (int j = 0; j < KM; j++) { lv[j] = __expf(lv[j] - m); s += lv[j]; }
                float inv = 1.f / s;
                #pragma unroll
                for (int j = 0; j < KM; j++) Lr[HKC + h*KM + j] = (bf16)(lv[j]*inv);
            }
        }
    }
    __syncthreads();
    {
        float s = 0.f;
        for (int r = 0; r < 128; r++) s += (float)u.Ls[r*264 + tid];
        if (tid < NTOT) atomicAdd(&A2[b*NPAD + tid], s);
    }
}

// ---------------- finalize ----------------
__global__ __launch_bounds__(256) void finalize_kernel(const float* __restrict__ A2, const float* __restrict__ W2,
                                                       const float* __restrict__ cbo, const float* __restrict__ mbo,
                                                       const float* __restrict__ P, float* __restrict__ out)
{
    __shared__ float a[NTOT];
    int b = blockIdx.x, tid = threadIdx.x;
    if (tid < NTOT) a[tid] = A2[b*NPAD + tid];
    __syncthreads();
    float invP = 1.f / P[b];
    for (int j = tid; j < 512; j += 256) {
        float pc = 2048.f*cbo[j], pm = 2048.f*mbo[j];
        for (int n = 0; n < HKC; n++) pc += a[n]*W2[n*512 + j];
        for (int n = HKC; n < NTOT; n++) pm += a[n]*W2[n*512 + j];
        out[b*512 + j] = pc*invP;
        out[BATCH*512 + b*512 + j] = (pc - pm)*invP;
    }
}

extern "C" void kernel_launch(void* const* d_in, const int* in_sizes, int n_in,
                              void* d_out, int out_size, void* d_ws, size_t ws_size,
                              hipStream_t stream)
{
    (void)in_sizes; (void)n_in; (void)out_size;
    const float* emb   = (const float*)d_in[0];
    const int* emask   = (const int*)d_in[1];
    const int* pmask   = (const int*)d_in[2];
    /* d_in[3] frame_mask: cancels in softmax */
    const int* cmask   = (const int*)d_in[4];
    const int* mmask   = (const int*)d_in[5];
    const float* W_lin = (const float*)d_in[6];
    const float* b_lin = (const float*)d_in[7];
    const float* ctab  = (const float*)d_in[8];
    const float* mtab  = (const float*)d_in[9];
    const float* cWq = (const float*)d_in[10]; const float* cbq = (const float*)d_in[11];
    const float* cWk = (const float*)d_in[12]; const float* cbk = (const float*)d_in[13];
    const float* cWv = (const float*)d_in[14]; const float* cbv = (const float*)d_in[15];
    const float* cWo = (const float*)d_in[16]; const float* cbo = (const float*)d_in[17];
    const float* mWq = (const float*)d_in[18]; const float* mbq = (const float*)d_in[19];
    const float* mWk = (const float*)d_in[20]; const float* mbk = (const float*)d_in[21];
    const float* mWv = (const float*)d_in[22]; const float* mbv = (const float*)d_in[23];
    const float* mWo = (const float*)d_in[24]; const float* mbo = (const float*)d_in[25];
    float* outp = (float*)d_out;

    if (ws_size < 40000000UL) return;

    char* ws = (char*)d_ws;
    size_t o = 0;
    bf16* av1   = (bf16*)(ws + o); o += (size_t)65536*NPAD*2;   // 33.5 MB
    bf16* Bt    = (bf16*)(ws + o); o += 256*1024*2;
    bf16* GT    = (bf16*)(ws + o); o += NPAD*NPAD*2;
    float* k1c  = (float*)(ws + o); o += KC*512*4;
    float* v1c  = (float*)(ws + o); o += KC*512*4;
    float* k1m  = (float*)(ws + o); o += KM*512*4;
    float* v1m  = (float*)(ws + o); o += KM*512*4;
    float* MqTd = (float*)(ws + o); o += (size_t)512*NPAD*4;
    float* W2   = (float*)(ws + o); o += (size_t)NTOT*512*4;
    float* c1   = (float*)(ws + o); o += NPAD*4;
    float* c2   = (float*)(ws + o); o += NPAD*4;
    float* mbt  = (float*)(ws + o); o += BATCH*NPAD*4;
    float* P    = (float*)(ws + o); o += 128;
    float* A2   = (float*)(ws + o); o += BATCH*NPAD*4;

    dim3 blk(256);

    prep1<<<dim3(65), blk, 0, stream>>>(emask, pmask, cmask, mmask, ctab, mtab,
                                        cWk, cbk, cWv, cbv, mWk, mbk, mWv, mbv,
                                        P, A2, mbt, k1c, v1c, k1m, v1m, GT, Bt, c1, c2);
    prep2<<<dim3(744), blk, 0, stream>>>(cWq, mWq, k1c, v1c, k1m, v1m, cWo, mWo, MqTd, W2);
    prep3<<<dim3(361), blk, 0, stream>>>(W_lin, b_lin, MqTd, W2, k1c, k1m,
                                         cbq, mbq, cbo, mbo, Bt, GT, c1, c2);
    g1_kernel<<<dim3(512), blk, 0, stream>>>(emb, Bt, c1, mbt, av1);
    g2_kernel<<<dim3(512), blk, 0, stream>>>(av1, GT, c2, mbt, A2);
    finalize_kernel<<<dim3(BATCH), blk, 0, stream>>>(A2, W2, cbo, mbo, P, outp);
}